// Round 8
// baseline (332.703 us; speedup 1.0000x reference)
//
#include <hip/hip_runtime.h>
#include <hip/hip_bf16.h>
#include <cmath>

#define HH 512
#define WW 512
#define NIMG 12
#define RES (HH*WW)
#define NBINS 256
#define PXB 1024            // TWO image rows per block; 3 waves, 1 predictor each

typedef __attribute__((ext_vector_type(8))) short bf8;     // 8 bf16 (4 VGPR) MFMA A/B frag
typedef __attribute__((ext_vector_type(4))) float f32x4;   // MFMA C/D frag
typedef __attribute__((ext_vector_type(2))) float f32x2;

__device__ __forceinline__ unsigned bf_rne(float x) {      // f32 -> bf16 bits (setup path)
    unsigned u = __float_as_uint(x);
    return (u + 0x7fffu + ((u >> 16) & 1u)) >> 16;
}

// HW packed f32x2 -> bf16x2 (RNE)
__device__ __forceinline__ unsigned cvtpk(float a, float b) {
    unsigned r;
    asm("v_cvt_pk_bf16_f32 %0, %1, %2" : "=v"(r) : "v"(a), "v"(b));
    return r;
}
// packed dual-f32 multiply (one VALU slot for two muls)
__device__ __forceinline__ f32x2 pkmul(f32x2 a, f32x2 b) {
    f32x2 r;
    asm("v_pk_mul_f32 %0, %1, %2" : "=v"(r) : "v"(a), "v"(b));
    return r;
}

union bf8u { bf8 f; unsigned u[4]; };

// leaky-relu on 2 elements + pack to bf16x2: pk_mul + 2 max + cvtpk
__device__ __forceinline__ unsigned actpair(float x0, float x1, f32x2 k) {
    f32x2 a; a[0] = x0; a[1] = x1;
    const f32x2 p = pkmul(a, k);
    return cvtpk(fmaxf(x0, p[0]), fmaxf(x1, p[1]));
}

// C/D frag pair -> next layer's B frag WITH leaky-relu
// (valid because producing layer's rows are sigma-permuted)
__device__ __forceinline__ bf8 actfrag(const f32x4 a0, const f32x4 a1, f32x2 k) {
    bf8u r;
    r.u[0] = actpair(a0[0], a0[1], k);
    r.u[1] = actpair(a0[2], a0[3], k);
    r.u[2] = actpair(a1[0], a1[1], k);
    r.u[3] = actpair(a1[2], a1[3], k);
    return r.f;
}

#define MFMA(A, B, C) __builtin_amdgcn_mfma_f32_16x16x32_bf16((A), (B), (C), 0, 0, 0)

// one predictor, one 16-px tile: 7 MFMAs, unfused VALU activation.
__device__ __forceinline__ void run_pred_tile(
    const bf8 w0a, const bf8 w0b,
    const bf8 w1a, const bf8 w1b,
    const bf8 w2a, const bf8 w2b,
    const bf8 w3f,
    const f32x4 c10, const f32x4 c11, const f32x4 c20, const f32x4 c21,
    const bf8 pf, f32x4& acc3, const f32x2 k)
{
    const f32x4 z = {0.f, 0.f, 0.f, 0.f};
    f32x4 za = MFMA(w0a, pf, z);
    f32x4 zb = MFMA(w0b, pf, z);
    bf8 h = actfrag(za, zb, k);
    za = MFMA(w1a, h, c10);
    zb = MFMA(w1b, h, c11);
    h = actfrag(za, zb, k);
    za = MFMA(w2a, h, c20);
    zb = MFMA(w2b, h, c21);
    h = actfrag(za, zb, k);
    acc3 = MFMA(w3f, h, acc3);
}

// patch B-frag from staged LDS rows: 4 dword reads (imm offsets), q==3 patches bias
__device__ __forceinline__ bf8 build_pf(const unsigned* __restrict__ rb, int tt, int q) {
    bf8u r;
    r.u[0] = rb[8*tt + 0];
    r.u[1] = rb[8*tt + 1];
    unsigned u2 = rb[8*tt + 2];
    unsigned u3 = rb[8*tt + 3];
    if (q == 3) { u2 = 0x00003f80u; u3 = 0u; }   // (bias=1.0, 0), (0,0)
    r.u[2] = u2; r.u[3] = u3;
    return r.f;
}

#define RBW 260            // words per staged row copy (4-px pads both sides)

__global__ __launch_bounds__(192, 5) void codec_main(
    const float* __restrict__ x,
    const float* __restrict__ a_wT, const float* __restrict__ a_bT, const float* __restrict__ a_wL,
    const float* __restrict__ a_w1, const float* __restrict__ a_b1,
    const float* __restrict__ a_w2, const float* __restrict__ a_b2,
    const float* __restrict__ a_w3, const float* __restrict__ a_b3,
    const float* __restrict__ b_wT, const float* __restrict__ b_bT, const float* __restrict__ b_wL,
    const float* __restrict__ b_w1, const float* __restrict__ b_b1,
    const float* __restrict__ b_w2, const float* __restrict__ b_b2,
    const float* __restrict__ b_w3, const float* __restrict__ b_b3,
    const float* __restrict__ c_wT, const float* __restrict__ c_bT, const float* __restrict__ c_wL,
    const float* __restrict__ c_w1, const float* __restrict__ c_b1,
    const float* __restrict__ c_w2, const float* __restrict__ c_b2,
    const float* __restrict__ c_w3, const float* __restrict__ c_b3,
    float* __restrict__ sums,
    unsigned* __restrict__ ticket,
    unsigned* __restrict__ hist_x,
    unsigned* __restrict__ hist_d,
    float* __restrict__ out)
{
    // dual-parity bf16 row staging for rows i0-3 .. i0+1 (5 rows):
    //   copyA word w = (px[2w-4], px[2w-3]) ; copyB word w = (px[2w-3], px[2w-2])
    //   output row i0   uses rowbuf[0..3]  (q -> rowbuf[q])
    //   output row i0+1 uses rowbuf[1..4]  (q -> rowbuf[q+1])  -- layout shift-invariant
    __shared__ unsigned rowbuf[5][2][RBW];
    __shared__ float predb[3][PXB];     // clipped predictions, one row per predictor
    __shared__ unsigned shx[NBINS], shd[NBINS];
    __shared__ float red[8];
    __shared__ unsigned lastflag;

    const int tid  = threadIdx.x;       // 0..191
    const int lane = tid & 63;
    const int wv   = tid >> 6;          // 0..2 == predictor index
    const int q    = lane >> 4;         // quad group: patch row (K-layout); C/D rows 4q+r
    const int m16  = lane & 15;         // m (A) / n=pixel (B, C/D)

    for (int k = tid; k < NBINS; k += 192) { shx[k] = 0u; shd[k] = 0u; }

    // this wave's predictor weight pointers (wave-uniform selects)
    const float* wT = (wv == 0) ? a_wT : ((wv == 1) ? b_wT : c_wT);
    const float* bT = (wv == 0) ? a_bT : ((wv == 1) ? b_bT : c_bT);
    const float* wL = (wv == 0) ? a_wL : ((wv == 1) ? b_wL : c_wL);
    const float* w1 = (wv == 0) ? a_w1 : ((wv == 1) ? b_w1 : c_w1);
    const float* b1 = (wv == 0) ? a_b1 : ((wv == 1) ? b_b1 : c_b1);
    const float* w2 = (wv == 0) ? a_w2 : ((wv == 1) ? b_w2 : c_w2);
    const float* b2 = (wv == 0) ? a_b2 : ((wv == 1) ? b_b2 : c_b2);
    const float* w3 = (wv == 0) ? a_w3 : ((wv == 1) ? b_w3 : c_w3);
    const float* b3 = (wv == 0) ? a_b3 : ((wv == 1) ? b_b3 : c_b3);

    // ---- one-time: weights -> MFMA A-frags (rows sigma-permuted), row-aligned K-layout ----
    // q<3  : k=8q+j, row (i-3+q), col (c-3+j), j==7 -> weight 0 (pad slot)
    // q==3 : j=0..2 -> wL cols c-3..c-1 ; j==3 -> 0 ; j==4 -> bias(bT) ; j>=5 -> 0
    bf8 wA0[2], wA1[2], wA2[2], aw3;
    f32x4 cb1[2], cb2[2];              // f32 bias C-inits (registers, loaded once)
    #pragma unroll
    for (int mt = 0; mt < 2; ++mt) {
        const int ch = ((m16 >> 2) << 3) + (mt << 2) + (m16 & 3);   // sigma(16mt+m16)
        bf8 f0;
        #pragma unroll
        for (int j = 0; j < 8; ++j) {
            float v = 0.0f;
            if (q < 3) { if (j < 7) v = wT[ch*21 + q*7 + j]; }
            else       { if (j < 3) v = wL[ch*3 + j]; else if (j == 4) v = bT[ch]; }
            f0[j] = (short)bf_rne(v);
        }
        wA0[mt] = f0;
        {
            const f32x4 lo = *(const f32x4*)&w1[ch*32 + 8*q];
            const f32x4 hi = *(const f32x4*)&w1[ch*32 + 8*q + 4];
            bf8 g;
            #pragma unroll
            for (int j = 0; j < 4; ++j) { g[j] = (short)bf_rne(lo[j]); g[4+j] = (short)bf_rne(hi[j]); }
            wA1[mt] = g;
        }
        {
            const f32x4 lo = *(const f32x4*)&w2[ch*32 + 8*q];
            const f32x4 hi = *(const f32x4*)&w2[ch*32 + 8*q + 4];
            bf8 g;
            #pragma unroll
            for (int j = 0; j < 4; ++j) { g[j] = (short)bf_rne(lo[j]); g[4+j] = (short)bf_rne(hi[j]); }
            wA2[mt] = g;
        }
        // bias rows: computed row 16mt+4q+r -> logical sigma = 8q+4mt+r
        if (mt == 0) { cb1[0] = *(const f32x4*)&b1[8*q];     cb2[0] = *(const f32x4*)&b2[8*q]; }
        else         { cb1[1] = *(const f32x4*)&b1[8*q + 4]; cb2[1] = *(const f32x4*)&b2[8*q + 4]; }
    }
    // L3 A-frag: w3 in row 0 only (columns natural: sigma fixed-point)
    {
        bf8 g;
        #pragma unroll
        for (int j = 0; j < 8; ++j) {
            const float v = (m16 == 0) ? w3[8*q + j] : 0.0f;
            g[j] = (short)bf_rne(v);
        }
        aw3 = g;
    }
    // L3 bias C-init: row 0 (q==0, reg 0)
    f32x4 bias3v = {0.f, 0.f, 0.f, 0.f};
    if (q == 0) bias3v[0] = b3[0];

    f32x2 k001; k001[0] = 0.01f; k001[1] = 0.01f;

    const int img = blockIdx.y;
    const float* __restrict__ X = x + (size_t)img * RES;
    // XCD-aware row-pair swizzle: band of 32 consecutive pairs per XCD (256 % 8 == 0, bijective)
    const int bx = blockIdx.x;                       // 0..255 (row pair)
    const int i0 = (((bx & 7) << 5) | (bx >> 3)) << 1;   // first image row of the pair

    // ---- cooperative staging: 5 rows -> dual-parity bf16 (zero-padded; handles all edges) ----
    for (int w = tid; w < 5*2*RBW; w += 192) {
        const int r   = w / (2*RBW);      // 0..4: rows i0-3 .. i0+1
        const int rem = w - r*(2*RBW);
        const int cp  = rem / RBW;        // 0=A, 1=B
        const int wd  = rem - cp*RBW;
        const int srcrow = i0 - 3 + r;
        const int p0 = 2*wd - 4 + cp;     // A: 2wd-4 ; B: 2wd-3
        float f0 = 0.0f, f1 = 0.0f;
        if (srcrow >= 0) {
            if ((unsigned)p0 < (unsigned)WW)       f0 = X[srcrow*WW + p0];
            if ((unsigned)(p0+1) < (unsigned)WW)   f1 = X[srcrow*WW + p0 + 1];
        }
        rowbuf[r][cp][wd] = cvtpk(f0, f1);
    }
    __syncthreads();

    // per-lane LDS column: parity-selected copy, first word for tile 0
    const int cp = 1 - (m16 & 1);             // m16 odd -> copyA, even -> copyB
    const int w0 = (m16 + 1) >> 1;

    #pragma unroll 1
    for (int r2 = 0; r2 < 2; ++r2) {
        const unsigned* __restrict__ rb = &rowbuf[q + r2][cp][w0];
        const int pb0 = r2 << 9;          // predb offset for this output row

        #pragma unroll 1
        for (int u = 0; u < 8; ++u) {
            // ---- pair 0: tiles 4u+0, 4u+1 ----
            {
                const bf8 pfa = build_pf(rb, 4*u + 0, q);
                const bf8 pfb = build_pf(rb, 4*u + 1, q);
                f32x4 acc0 = bias3v, acc1 = bias3v;
                run_pred_tile(wA0[0], wA0[1], wA1[0], wA1[1], wA2[0], wA2[1], aw3,
                              cb1[0], cb1[1], cb2[0], cb2[1], pfa, acc0, k001);
                run_pred_tile(wA0[0], wA0[1], wA1[0], wA1[1], wA2[0], wA2[1], aw3,
                              cb1[0], cb1[1], cb2[0], cb2[1], pfb, acc1, k001);
                if (q == 0) {
                    predb[wv][pb0 + 64*u      + m16] = fminf(fmaxf(acc0[0], -1.0f), 1.0f);
                    predb[wv][pb0 + 64*u + 16 + m16] = fminf(fmaxf(acc1[0], -1.0f), 1.0f);
                }
            }
            // ---- pair 1: tiles 4u+2, 4u+3 ----
            {
                const bf8 pfa = build_pf(rb, 4*u + 2, q);
                const bf8 pfb = build_pf(rb, 4*u + 3, q);
                f32x4 acc0 = bias3v, acc1 = bias3v;
                run_pred_tile(wA0[0], wA0[1], wA1[0], wA1[1], wA2[0], wA2[1], aw3,
                              cb1[0], cb1[1], cb2[0], cb2[1], pfa, acc0, k001);
                run_pred_tile(wA0[0], wA0[1], wA1[0], wA1[1], wA2[0], wA2[1], aw3,
                              cb1[0], cb1[1], cb2[0], cb2[1], pfb, acc1, k001);
                if (q == 0) {
                    predb[wv][pb0 + 64*u + 32 + m16] = fminf(fmaxf(acc0[0], -1.0f), 1.0f);
                    predb[wv][pb0 + 64*u + 48 + m16] = fminf(fmaxf(acc1[0], -1.0f), 1.0f);
                }
            }
        }
    }

    __syncthreads();

    // ---- stats: all 192 threads cooperatively over the block's 1024 px (2 rows, contiguous) ----
    float sx = 0.0f, sd = 0.0f;
    const float* __restrict__ Xrow = X + i0*WW;
    for (int idx = tid; idx < PXB; idx += 192) {
        const float xv = Xrow[idx];                    // L1/L2-hot reload
        const float pa = predb[0][idx];
        const float pb = predb[1][idx];
        const float pc = predb[2][idx];
        const float med = fmaxf(fminf(pa, fmaxf(pb, pc)), fminf(pb, pc));
        const float v = xv - med + 1.0f;               // in (-1, 3)
        const float delta = ((v >= 2.0f) ? v - 2.0f : v) - 1.0f;   // == fmodf(v,2)-1 exactly
        int bx2 = (int)floorf((xv + 1.0f) * 128.0f);
        bx2 = bx2 < 0 ? 0 : (bx2 > 255 ? 255 : bx2);
        if (xv >= -1.0f && xv <= 1.0f) atomicAdd(&shx[bx2], 1u);
        int bd = (int)floorf((delta + 1.0f) * 128.0f);
        bd = bd < 0 ? 0 : (bd > 255 ? 255 : bd);
        if (delta >= -1.0f && delta <= 1.0f) atomicAdd(&shd[bd], 1u);
        sx += xv*xv; sd += delta*delta;
    }

    // ---- block reduction ----
    #pragma unroll
    for (int off = 32; off > 0; off >>= 1) {
        sx += __shfl_down(sx, off);
        sd += __shfl_down(sd, off);
    }
    if (lane == 0) { red[wv] = sx; red[4 + wv] = sd; }
    __syncthreads();
    if (tid == 0) {
        atomicAdd(&sums[0], red[0] + red[1] + red[2]);
        atomicAdd(&sums[1], red[4] + red[5] + red[6]);
    }
    for (int k = tid; k < NBINS; k += 192) {
        if (shx[k]) atomicAdd(&hist_x[img*NBINS + k], shx[k]);
        if (shd[k]) atomicAdd(&hist_d[img*NBINS + k], shd[k]);
    }

    // ---- last-block fused finalization (pattern correctness-proven in R4) ----
    __threadfence();                                   // release our global atomics
    if (tid == 0) {
        const unsigned total = gridDim.x * gridDim.y;
        const unsigned t = atomicAdd(ticket, 1u);
        lastflag = (t == total - 1u) ? 1u : 0u;
    }
    __syncthreads();
    if (lastflag) {
        __threadfence();                               // acquire side
        float ex = 0.0f, ed = 0.0f;
        const float inv_res = 1.0f / (float)RES;
        for (int k = tid; k < NIMG*NBINS; k += 192) {
            const unsigned hx = __hip_atomic_load(&hist_x[k], __ATOMIC_RELAXED, __HIP_MEMORY_SCOPE_AGENT);
            const unsigned hd = __hip_atomic_load(&hist_d[k], __ATOMIC_RELAXED, __HIP_MEMORY_SCOPE_AGENT);
            if (hx) { const float p = (float)hx * inv_res; ex -= p * log2f(p); }
            if (hd) { const float p = (float)hd * inv_res; ed -= p * log2f(p); }
        }
        #pragma unroll
        for (int off = 32; off > 0; off >>= 1) {
            ex += __shfl_down(ex, off);
            ed += __shfl_down(ed, off);
        }
        __syncthreads();                               // red[] reuse: prior use done
        if (lane == 0) { red[wv] = ex; red[4 + wv] = ed; }
        __syncthreads();
        if (tid == 0) {
            const float Ex = red[0] + red[1] + red[2];
            const float Ed = red[4] + red[5] + red[6];
            const float s0 = __hip_atomic_load(&sums[0], __ATOMIC_RELAXED, __HIP_MEMORY_SCOPE_AGENT);
            const float s1 = __hip_atomic_load(&sums[1], __ATOMIC_RELAXED, __HIP_MEMORY_SCOPE_AGENT);
            const float inv_n = 1.0f / (float)(NIMG * RES);
            out[0] = 255.0f * sqrtf(s1 * inv_n);       // loss1 (deltas)
            out[1] = 255.0f * sqrtf(s0 * inv_n);       // loss0 (x)
            out[2] = Ex / (8.0f * (float)NIMG);        // invCR0
            out[3] = Ed / (8.0f * (float)NIMG);        // invCR1
        }
    }
}

extern "C" void kernel_launch(void* const* d_in, const int* in_sizes, int n_in,
                              void* d_out, int out_size, void* d_ws, size_t ws_size,
                              hipStream_t stream)
{
    const float* x = (const float*)d_in[0];
    const float* w[27];
    for (int k = 0; k < 27; ++k) w[k] = (const float*)d_in[1 + k];

    float*    sums   = (float*)d_ws;                       // [0],[1] float sums
    unsigned* ticket = (unsigned*)((char*)d_ws + 8);       // completion ticket
    unsigned* hist_x = (unsigned*)((char*)d_ws + 16);
    unsigned* hist_d = hist_x + NIMG*NBINS;
    const size_t zbytes = 16 + (size_t)2*NIMG*NBINS*sizeof(unsigned);
    hipMemsetAsync(d_ws, 0, zbytes, stream);

    dim3 grid(HH/2, NIMG);
    codec_main<<<grid, dim3(192), 0, stream>>>(
        x,
        w[0],  w[1],  w[2],  w[3],  w[4],  w[5],  w[6],  w[7],  w[8],
        w[9],  w[10], w[11], w[12], w[13], w[14], w[15], w[16], w[17],
        w[18], w[19], w[20], w[21], w[22], w[23], w[24], w[25], w[26],
        sums, ticket, hist_x, hist_d, (float*)d_out);
}

// Round 9
// 313.899 us; speedup vs baseline: 1.0599x; 1.0599x over previous
//
#include <hip/hip_runtime.h>
#include <hip/hip_bf16.h>
#include <cmath>

#define HH 512
#define WW 512
#define NIMG 12
#define RES (HH*WW)
#define NBINS 256
#define PXB 2048            // FOUR image rows per block; 6 waves = 3 predictors x 2 row-pairs

typedef __attribute__((ext_vector_type(8))) short bf8;     // 8 bf16 (4 VGPR) MFMA A/B frag
typedef __attribute__((ext_vector_type(4))) float f32x4;   // MFMA C/D frag
typedef __attribute__((ext_vector_type(2))) float f32x2;

__device__ __forceinline__ unsigned bf_rne(float x) {      // f32 -> bf16 bits (setup path)
    unsigned u = __float_as_uint(x);
    return (u + 0x7fffu + ((u >> 16) & 1u)) >> 16;
}

// HW packed f32x2 -> bf16x2 (RNE)
__device__ __forceinline__ unsigned cvtpk(float a, float b) {
    unsigned r;
    asm("v_cvt_pk_bf16_f32 %0, %1, %2" : "=v"(r) : "v"(a), "v"(b));
    return r;
}
// packed dual-f32 multiply (one VALU slot for two muls)
__device__ __forceinline__ f32x2 pkmul(f32x2 a, f32x2 b) {
    f32x2 r;
    asm("v_pk_mul_f32 %0, %1, %2" : "=v"(r) : "v"(a), "v"(b));
    return r;
}

union bf8u { bf8 f; unsigned u[4]; };

// leaky-relu on 2 elements + pack to bf16x2: pk_mul + 2 max + cvtpk
__device__ __forceinline__ unsigned actpair(float x0, float x1, f32x2 k) {
    f32x2 a; a[0] = x0; a[1] = x1;
    const f32x2 p = pkmul(a, k);
    return cvtpk(fmaxf(x0, p[0]), fmaxf(x1, p[1]));
}

// C/D frag pair -> next layer's B frag WITH leaky-relu
// (valid because producing layer's rows are sigma-permuted)
__device__ __forceinline__ bf8 actfrag(const f32x4 a0, const f32x4 a1, f32x2 k) {
    bf8u r;
    r.u[0] = actpair(a0[0], a0[1], k);
    r.u[1] = actpair(a0[2], a0[3], k);
    r.u[2] = actpair(a1[0], a1[1], k);
    r.u[3] = actpair(a1[2], a1[3], k);
    return r.f;
}

#define MFMA(A, B, C) __builtin_amdgcn_mfma_f32_16x16x32_bf16((A), (B), (C), 0, 0, 0)

// one predictor, one 16-px tile: 7 MFMAs, unfused VALU activation.
__device__ __forceinline__ void run_pred_tile(
    const bf8 w0a, const bf8 w0b,
    const bf8 w1a, const bf8 w1b,
    const bf8 w2a, const bf8 w2b,
    const bf8 w3f,
    const f32x4 c10, const f32x4 c11, const f32x4 c20, const f32x4 c21,
    const bf8 pf, f32x4& acc3, const f32x2 k)
{
    const f32x4 z = {0.f, 0.f, 0.f, 0.f};
    f32x4 za = MFMA(w0a, pf, z);
    f32x4 zb = MFMA(w0b, pf, z);
    bf8 h = actfrag(za, zb, k);
    za = MFMA(w1a, h, c10);
    zb = MFMA(w1b, h, c11);
    h = actfrag(za, zb, k);
    za = MFMA(w2a, h, c20);
    zb = MFMA(w2b, h, c21);
    h = actfrag(za, zb, k);
    acc3 = MFMA(w3f, h, acc3);
}

// patch B-frag from staged LDS rows: 4 dword reads (imm offsets), q==3 patches bias
__device__ __forceinline__ bf8 build_pf(const unsigned* __restrict__ rb, int tt, int q) {
    bf8u r;
    r.u[0] = rb[8*tt + 0];
    r.u[1] = rb[8*tt + 1];
    unsigned u2 = rb[8*tt + 2];
    unsigned u3 = rb[8*tt + 3];
    if (q == 3) { u2 = 0x00003f80u; u3 = 0u; }   // (bias=1.0, 0), (0,0)
    r.u[2] = u2; r.u[3] = u3;
    return r.f;
}

#define RBW 260            // words per staged row copy (4-px pads both sides)

__global__ __launch_bounds__(384, 4) void codec_main(
    const float* __restrict__ x,
    const float* __restrict__ a_wT, const float* __restrict__ a_bT, const float* __restrict__ a_wL,
    const float* __restrict__ a_w1, const float* __restrict__ a_b1,
    const float* __restrict__ a_w2, const float* __restrict__ a_b2,
    const float* __restrict__ a_w3, const float* __restrict__ a_b3,
    const float* __restrict__ b_wT, const float* __restrict__ b_bT, const float* __restrict__ b_wL,
    const float* __restrict__ b_w1, const float* __restrict__ b_b1,
    const float* __restrict__ b_w2, const float* __restrict__ b_b2,
    const float* __restrict__ b_w3, const float* __restrict__ b_b3,
    const float* __restrict__ c_wT, const float* __restrict__ c_bT, const float* __restrict__ c_wL,
    const float* __restrict__ c_w1, const float* __restrict__ c_b1,
    const float* __restrict__ c_w2, const float* __restrict__ c_b2,
    const float* __restrict__ c_w3, const float* __restrict__ c_b3,
    float* __restrict__ sums,
    unsigned* __restrict__ hist_x,
    unsigned* __restrict__ hist_d)
{
    // dual-parity bf16 row staging for rows i0-3 .. i0+3 (7 rows):
    //   copyA word w = (px[2w-4], px[2w-3]) ; copyB word w = (px[2w-3], px[2w-2])
    //   output row i0+s uses rowbuf[s..s+3]  (q -> rowbuf[q+s])  -- layout shift-invariant
    __shared__ unsigned rowbuf[7][2][RBW];
    __shared__ float predb[3][PXB];     // clipped predictions, one plane per predictor
    __shared__ unsigned shx[NBINS], shd[NBINS];
    __shared__ float red[12];

    const int tid  = threadIdx.x;       // 0..383
    const int lane = tid & 63;
    const int wv   = tid >> 6;          // 0..5
    const int p    = (wv < 3) ? wv : wv - 3;   // predictor index
    const int rg   = (wv < 3) ? 0 : 1;         // row-pair group (rows i0+2rg, i0+2rg+1)
    const int q    = lane >> 4;         // quad group: patch row (K-layout); C/D rows 4q+r
    const int m16  = lane & 15;         // m (A) / n=pixel (B, C/D)

    for (int k = tid; k < NBINS; k += 384) { shx[k] = 0u; shd[k] = 0u; }

    // this wave's predictor weight pointers (wave-uniform selects)
    const float* wT = (p == 0) ? a_wT : ((p == 1) ? b_wT : c_wT);
    const float* bT = (p == 0) ? a_bT : ((p == 1) ? b_bT : c_bT);
    const float* wL = (p == 0) ? a_wL : ((p == 1) ? b_wL : c_wL);
    const float* w1 = (p == 0) ? a_w1 : ((p == 1) ? b_w1 : c_w1);
    const float* b1 = (p == 0) ? a_b1 : ((p == 1) ? b_b1 : c_b1);
    const float* w2 = (p == 0) ? a_w2 : ((p == 1) ? b_w2 : c_w2);
    const float* b2 = (p == 0) ? a_b2 : ((p == 1) ? b_b2 : c_b2);
    const float* w3 = (p == 0) ? a_w3 : ((p == 1) ? b_w3 : c_w3);
    const float* b3 = (p == 0) ? a_b3 : ((p == 1) ? b_b3 : c_b3);

    // ---- one-time: weights -> MFMA A-frags (rows sigma-permuted), row-aligned K-layout ----
    // q<3  : k=8q+j, row (i-3+q), col (c-3+j), j==7 -> weight 0 (pad slot)
    // q==3 : j=0..2 -> wL cols c-3..c-1 ; j==3 -> 0 ; j==4 -> bias(bT) ; j>=5 -> 0
    bf8 wA0[2], wA1[2], wA2[2], aw3;
    f32x4 cb1[2], cb2[2];              // f32 bias C-inits (registers, loaded once)
    #pragma unroll
    for (int mt = 0; mt < 2; ++mt) {
        const int ch = ((m16 >> 2) << 3) + (mt << 2) + (m16 & 3);   // sigma(16mt+m16)
        bf8 f0;
        #pragma unroll
        for (int j = 0; j < 8; ++j) {
            float v = 0.0f;
            if (q < 3) { if (j < 7) v = wT[ch*21 + q*7 + j]; }
            else       { if (j < 3) v = wL[ch*3 + j]; else if (j == 4) v = bT[ch]; }
            f0[j] = (short)bf_rne(v);
        }
        wA0[mt] = f0;
        {
            const f32x4 lo = *(const f32x4*)&w1[ch*32 + 8*q];
            const f32x4 hi = *(const f32x4*)&w1[ch*32 + 8*q + 4];
            bf8 g;
            #pragma unroll
            for (int j = 0; j < 4; ++j) { g[j] = (short)bf_rne(lo[j]); g[4+j] = (short)bf_rne(hi[j]); }
            wA1[mt] = g;
        }
        {
            const f32x4 lo = *(const f32x4*)&w2[ch*32 + 8*q];
            const f32x4 hi = *(const f32x4*)&w2[ch*32 + 8*q + 4];
            bf8 g;
            #pragma unroll
            for (int j = 0; j < 4; ++j) { g[j] = (short)bf_rne(lo[j]); g[4+j] = (short)bf_rne(hi[j]); }
            wA2[mt] = g;
        }
        // bias rows: computed row 16mt+4q+r -> logical sigma = 8q+4mt+r
        if (mt == 0) { cb1[0] = *(const f32x4*)&b1[8*q];     cb2[0] = *(const f32x4*)&b2[8*q]; }
        else         { cb1[1] = *(const f32x4*)&b1[8*q + 4]; cb2[1] = *(const f32x4*)&b2[8*q + 4]; }
    }
    // L3 A-frag: w3 in row 0 only (columns natural: sigma fixed-point)
    {
        bf8 g;
        #pragma unroll
        for (int j = 0; j < 8; ++j) {
            const float v = (m16 == 0) ? w3[8*q + j] : 0.0f;
            g[j] = (short)bf_rne(v);
        }
        aw3 = g;
    }
    // L3 bias C-init: row 0 (q==0, reg 0)
    f32x4 bias3v = {0.f, 0.f, 0.f, 0.f};
    if (q == 0) bias3v[0] = b3[0];

    f32x2 k001; k001[0] = 0.01f; k001[1] = 0.01f;

    const int img = blockIdx.y;
    const float* __restrict__ X = x + (size_t)img * RES;
    // XCD-aware row-quad swizzle: band of 16 consecutive quads per XCD (128 % 8 == 0, bijective)
    const int bx = blockIdx.x;                            // 0..127 (row quad)
    const int i0 = (((bx & 7) << 4) | (bx >> 3)) << 2;    // first image row of the quad

    // ---- cooperative staging: 7 rows -> dual-parity bf16 (zero-padded; handles all edges) ----
    for (int w = tid; w < 7*2*RBW; w += 384) {
        const int r   = w / (2*RBW);      // 0..6: rows i0-3 .. i0+3
        const int rem = w - r*(2*RBW);
        const int cp  = rem / RBW;        // 0=A, 1=B
        const int wd  = rem - cp*RBW;
        const int srcrow = i0 - 3 + r;    // max i0+3 <= 511, no upper guard needed
        const int p0 = 2*wd - 4 + cp;     // A: 2wd-4 ; B: 2wd-3
        float f0 = 0.0f, f1 = 0.0f;
        if (srcrow >= 0) {
            if ((unsigned)p0 < (unsigned)WW)       f0 = X[srcrow*WW + p0];
            if ((unsigned)(p0+1) < (unsigned)WW)   f1 = X[srcrow*WW + p0 + 1];
        }
        rowbuf[r][cp][wd] = cvtpk(f0, f1);
    }
    __syncthreads();

    // per-lane LDS column: parity-selected copy, first word for tile 0
    const int cp = 1 - (m16 & 1);             // m16 odd -> copyA, even -> copyB
    const int w0 = (m16 + 1) >> 1;

    #pragma unroll 1
    for (int r2 = 0; r2 < 2; ++r2) {
        const int srow = 2*rg + r2;                               // 0..3: output row i0+srow
        const unsigned* __restrict__ rb = &rowbuf[q + srow][cp][w0];
        const int pb0 = srow << 9;                                // predb offset for this row

        #pragma unroll 1
        for (int u = 0; u < 8; ++u) {
            // ---- pair 0: tiles 4u+0, 4u+1 ----
            {
                const bf8 pfa = build_pf(rb, 4*u + 0, q);
                const bf8 pfb = build_pf(rb, 4*u + 1, q);
                f32x4 acc0 = bias3v, acc1 = bias3v;
                run_pred_tile(wA0[0], wA0[1], wA1[0], wA1[1], wA2[0], wA2[1], aw3,
                              cb1[0], cb1[1], cb2[0], cb2[1], pfa, acc0, k001);
                run_pred_tile(wA0[0], wA0[1], wA1[0], wA1[1], wA2[0], wA2[1], aw3,
                              cb1[0], cb1[1], cb2[0], cb2[1], pfb, acc1, k001);
                if (q == 0) {
                    predb[p][pb0 + 64*u      + m16] = fminf(fmaxf(acc0[0], -1.0f), 1.0f);
                    predb[p][pb0 + 64*u + 16 + m16] = fminf(fmaxf(acc1[0], -1.0f), 1.0f);
                }
            }
            // ---- pair 1: tiles 4u+2, 4u+3 ----
            {
                const bf8 pfa = build_pf(rb, 4*u + 2, q);
                const bf8 pfb = build_pf(rb, 4*u + 3, q);
                f32x4 acc0 = bias3v, acc1 = bias3v;
                run_pred_tile(wA0[0], wA0[1], wA1[0], wA1[1], wA2[0], wA2[1], aw3,
                              cb1[0], cb1[1], cb2[0], cb2[1], pfa, acc0, k001);
                run_pred_tile(wA0[0], wA0[1], wA1[0], wA1[1], wA2[0], wA2[1], aw3,
                              cb1[0], cb1[1], cb2[0], cb2[1], pfb, acc1, k001);
                if (q == 0) {
                    predb[p][pb0 + 64*u + 32 + m16] = fminf(fmaxf(acc0[0], -1.0f), 1.0f);
                    predb[p][pb0 + 64*u + 48 + m16] = fminf(fmaxf(acc1[0], -1.0f), 1.0f);
                }
            }
        }
    }

    __syncthreads();

    // ---- stats: all 384 threads cooperatively over the block's 2048 px (4 rows, contiguous) ----
    float sx = 0.0f, sd = 0.0f;
    const float* __restrict__ Xrow = X + i0*WW;
    for (int idx = tid; idx < PXB; idx += 384) {
        const float xv = Xrow[idx];                    // L1/L2-hot reload
        const float pa = predb[0][idx];
        const float pb = predb[1][idx];
        const float pc = predb[2][idx];
        const float med = fmaxf(fminf(pa, fmaxf(pb, pc)), fminf(pb, pc));
        const float v = xv - med + 1.0f;               // in (-1, 3)
        const float delta = ((v >= 2.0f) ? v - 2.0f : v) - 1.0f;   // == fmodf(v,2)-1 exactly
        int bx2 = (int)floorf((xv + 1.0f) * 128.0f);
        bx2 = bx2 < 0 ? 0 : (bx2 > 255 ? 255 : bx2);
        if (xv >= -1.0f && xv <= 1.0f) atomicAdd(&shx[bx2], 1u);
        int bd = (int)floorf((delta + 1.0f) * 128.0f);
        bd = bd < 0 ? 0 : (bd > 255 ? 255 : bd);
        if (delta >= -1.0f && delta <= 1.0f) atomicAdd(&shd[bd], 1u);
        sx += xv*xv; sd += delta*delta;
    }

    // ---- block reduction ----
    #pragma unroll
    for (int off = 32; off > 0; off >>= 1) {
        sx += __shfl_down(sx, off);
        sd += __shfl_down(sd, off);
    }
    if (lane == 0) { red[wv] = sx; red[6 + wv] = sd; }
    __syncthreads();
    if (tid == 0) {
        atomicAdd(&sums[0], red[0] + red[1] + red[2] + red[3] + red[4] + red[5]);
        atomicAdd(&sums[1], red[6] + red[7] + red[8] + red[9] + red[10] + red[11]);
    }
    for (int k = tid; k < NBINS; k += 384) {
        if (shx[k]) atomicAdd(&hist_x[img*NBINS + k], shx[k]);
        if (shd[k]) atomicAdd(&hist_d[img*NBINS + k], shd[k]);
    }
}

__global__ __launch_bounds__(256) void codec_final(
    const float* __restrict__ sums,
    const unsigned* __restrict__ hist_x,
    const unsigned* __restrict__ hist_d,
    float* __restrict__ out)
{
    __shared__ float red[16];
    const int tid = threadIdx.x;
    float ex = 0.0f, ed = 0.0f;
    const float inv_res = 1.0f / (float)RES;
    for (int k = tid; k < NIMG*NBINS; k += 256) {
        const unsigned hx = hist_x[k];
        const unsigned hd = hist_d[k];
        if (hx) { const float p = (float)hx * inv_res; ex -= p * log2f(p); }
        if (hd) { const float p = (float)hd * inv_res; ed -= p * log2f(p); }
    }
    #pragma unroll
    for (int off = 32; off > 0; off >>= 1) {
        ex += __shfl_down(ex, off);
        ed += __shfl_down(ed, off);
    }
    const int lane = tid & 63, wv = tid >> 6;
    if (lane == 0) { red[wv] = ex; red[8 + wv] = ed; }
    __syncthreads();
    if (tid == 0) {
        const float Ex = red[0] + red[1] + red[2] + red[3];
        const float Ed = red[8] + red[9] + red[10] + red[11];
        const float inv_n = 1.0f / (float)(NIMG * RES);
        out[0] = 255.0f * sqrtf(sums[1] * inv_n);   // loss1 (deltas)
        out[1] = 255.0f * sqrtf(sums[0] * inv_n);   // loss0 (x)
        out[2] = Ex / (8.0f * (float)NIMG);         // invCR0
        out[3] = Ed / (8.0f * (float)NIMG);         // invCR1
    }
}

extern "C" void kernel_launch(void* const* d_in, const int* in_sizes, int n_in,
                              void* d_out, int out_size, void* d_ws, size_t ws_size,
                              hipStream_t stream)
{
    const float* x = (const float*)d_in[0];
    const float* w[27];
    for (int k = 0; k < 27; ++k) w[k] = (const float*)d_in[1 + k];

    float*    sums   = (float*)d_ws;
    unsigned* hist_x = (unsigned*)((char*)d_ws + 16);
    unsigned* hist_d = hist_x + NIMG*NBINS;
    const size_t zbytes = 16 + (size_t)2*NIMG*NBINS*sizeof(unsigned);
    hipMemsetAsync(d_ws, 0, zbytes, stream);

    dim3 grid(HH/4, NIMG);
    codec_main<<<grid, dim3(384), 0, stream>>>(
        x,
        w[0],  w[1],  w[2],  w[3],  w[4],  w[5],  w[6],  w[7],  w[8],
        w[9],  w[10], w[11], w[12], w[13], w[14], w[15], w[16], w[17],
        w[18], w[19], w[20], w[21], w[22], w[23], w[24], w[25], w[26],
        sums, hist_x, hist_d);
    codec_final<<<1, dim3(256), 0, stream>>>(sums, hist_x, hist_d, (float*)d_out);
}

// Round 10
// 279.574 us; speedup vs baseline: 1.1900x; 1.1228x over previous
//
#include <hip/hip_runtime.h>
#include <hip/hip_bf16.h>
#include <cmath>

#define HH 512
#define WW 512
#define NIMG 12
#define RES (HH*WW)
#define NBINS 256
#define PXB 1024            // TWO image rows per block; 3 waves, 1 predictor each

typedef __attribute__((ext_vector_type(8))) short bf8;     // 8 bf16 (4 VGPR) MFMA A/B frag
typedef __attribute__((ext_vector_type(4))) float f32x4;   // MFMA C/D frag
typedef __attribute__((ext_vector_type(2))) float f32x2;

__device__ __forceinline__ unsigned bf_rne(float x) {      // f32 -> bf16 bits (setup path)
    unsigned u = __float_as_uint(x);
    return (u + 0x7fffu + ((u >> 16) & 1u)) >> 16;
}

// HW packed f32x2 -> bf16x2 (RNE)
__device__ __forceinline__ unsigned cvtpk(float a, float b) {
    unsigned r;
    asm("v_cvt_pk_bf16_f32 %0, %1, %2" : "=v"(r) : "v"(a), "v"(b));
    return r;
}
// packed dual-f32 multiply (one VALU slot for two muls)
__device__ __forceinline__ f32x2 pkmul(f32x2 a, f32x2 b) {
    f32x2 r;
    asm("v_pk_mul_f32 %0, %1, %2" : "=v"(r) : "v"(a), "v"(b));
    return r;
}

union bf8u { bf8 f; unsigned u[4]; };

// leaky-relu on 2 elements + pack to bf16x2: pk_mul + 2 max + cvtpk
__device__ __forceinline__ unsigned actpair(float x0, float x1, f32x2 k) {
    f32x2 a; a[0] = x0; a[1] = x1;
    const f32x2 p = pkmul(a, k);
    return cvtpk(fmaxf(x0, p[0]), fmaxf(x1, p[1]));
}

// C/D frag pair -> next layer's B frag WITH leaky-relu
// (valid because producing layer's rows are sigma-permuted)
__device__ __forceinline__ bf8 actfrag(const f32x4 a0, const f32x4 a1, f32x2 k) {
    bf8u r;
    r.u[0] = actpair(a0[0], a0[1], k);
    r.u[1] = actpair(a0[2], a0[3], k);
    r.u[2] = actpair(a1[0], a1[1], k);
    r.u[3] = actpair(a1[2], a1[3], k);
    return r.f;
}

#define MFMA(A, B, C) __builtin_amdgcn_mfma_f32_16x16x32_bf16((A), (B), (C), 0, 0, 0)

// one predictor, one 16-px tile: 7 MFMAs, unfused VALU activation.
__device__ __forceinline__ void run_pred_tile(
    const bf8 w0a, const bf8 w0b,
    const bf8 w1a, const bf8 w1b,
    const bf8 w2a, const bf8 w2b,
    const bf8 w3f,
    const f32x4 c10, const f32x4 c11, const f32x4 c20, const f32x4 c21,
    const bf8 pf, f32x4& acc3, const f32x2 k)
{
    const f32x4 z = {0.f, 0.f, 0.f, 0.f};
    f32x4 za = MFMA(w0a, pf, z);
    f32x4 zb = MFMA(w0b, pf, z);
    bf8 h = actfrag(za, zb, k);
    za = MFMA(w1a, h, c10);
    zb = MFMA(w1b, h, c11);
    h = actfrag(za, zb, k);
    za = MFMA(w2a, h, c20);
    zb = MFMA(w2b, h, c21);
    h = actfrag(za, zb, k);
    acc3 = MFMA(w3f, h, acc3);
}

// patch B-frag from staged LDS rows: 4 dword reads (imm offsets), q==3 patches bias
__device__ __forceinline__ bf8 build_pf(const unsigned* __restrict__ rb, int tt, int q) {
    bf8u r;
    r.u[0] = rb[8*tt + 0];
    r.u[1] = rb[8*tt + 1];
    unsigned u2 = rb[8*tt + 2];
    unsigned u3 = rb[8*tt + 3];
    if (q == 3) { u2 = 0x00003f80u; u3 = 0u; }   // (bias=1.0, 0), (0,0)
    r.u[2] = u2; r.u[3] = u3;
    return r.f;
}

#define RBW 260            // words per staged row copy (4-px pads both sides)

__global__ __launch_bounds__(192, 4) void codec_main(
    const float* __restrict__ x,
    const float* __restrict__ a_wT, const float* __restrict__ a_bT, const float* __restrict__ a_wL,
    const float* __restrict__ a_w1, const float* __restrict__ a_b1,
    const float* __restrict__ a_w2, const float* __restrict__ a_b2,
    const float* __restrict__ a_w3, const float* __restrict__ a_b3,
    const float* __restrict__ b_wT, const float* __restrict__ b_bT, const float* __restrict__ b_wL,
    const float* __restrict__ b_w1, const float* __restrict__ b_b1,
    const float* __restrict__ b_w2, const float* __restrict__ b_b2,
    const float* __restrict__ b_w3, const float* __restrict__ b_b3,
    const float* __restrict__ c_wT, const float* __restrict__ c_bT, const float* __restrict__ c_wL,
    const float* __restrict__ c_w1, const float* __restrict__ c_b1,
    const float* __restrict__ c_w2, const float* __restrict__ c_b2,
    const float* __restrict__ c_w3, const float* __restrict__ c_b3,
    float* __restrict__ sums,
    unsigned* __restrict__ hist_x,
    unsigned* __restrict__ hist_d)
{
    // dual-parity bf16 row staging for rows i0-3 .. i0+1 (5 rows):
    //   copyA word w = (px[2w-4], px[2w-3]) ; copyB word w = (px[2w-3], px[2w-2])
    //   output row i0   uses rowbuf[0..3]  (q -> rowbuf[q])
    //   output row i0+1 uses rowbuf[1..4]  (q -> rowbuf[q+1])  -- layout shift-invariant
    __shared__ unsigned rowbuf[5][2][RBW];
    __shared__ float predb[3][PXB];     // clipped predictions, one row per predictor
    __shared__ unsigned shx[NBINS], shd[NBINS];
    __shared__ float red[8];

    const int tid  = threadIdx.x;       // 0..191
    const int lane = tid & 63;
    const int wv   = tid >> 6;          // 0..2 == predictor index
    const int q    = lane >> 4;         // quad group: patch row (K-layout); C/D rows 4q+r
    const int m16  = lane & 15;         // m (A) / n=pixel (B, C/D)

    for (int k = tid; k < NBINS; k += 192) { shx[k] = 0u; shd[k] = 0u; }

    // this wave's predictor weight pointers (wave-uniform selects)
    const float* wT = (wv == 0) ? a_wT : ((wv == 1) ? b_wT : c_wT);
    const float* bT = (wv == 0) ? a_bT : ((wv == 1) ? b_bT : c_bT);
    const float* wL = (wv == 0) ? a_wL : ((wv == 1) ? b_wL : c_wL);
    const float* w1 = (wv == 0) ? a_w1 : ((wv == 1) ? b_w1 : c_w1);
    const float* b1 = (wv == 0) ? a_b1 : ((wv == 1) ? b_b1 : c_b1);
    const float* w2 = (wv == 0) ? a_w2 : ((wv == 1) ? b_w2 : c_w2);
    const float* b2 = (wv == 0) ? a_b2 : ((wv == 1) ? b_b2 : c_b2);
    const float* w3 = (wv == 0) ? a_w3 : ((wv == 1) ? b_w3 : c_w3);
    const float* b3 = (wv == 0) ? a_b3 : ((wv == 1) ? b_b3 : c_b3);

    // ---- one-time: weights -> MFMA A-frags (rows sigma-permuted), row-aligned K-layout ----
    // q<3  : k=8q+j, row (i-3+q), col (c-3+j), j==7 -> weight 0 (pad slot)
    // q==3 : j=0..2 -> wL cols c-3..c-1 ; j==3 -> 0 ; j==4 -> bias(bT) ; j>=5 -> 0
    bf8 wA0[2], wA1[2], wA2[2], aw3;
    f32x4 cb1[2], cb2[2];              // f32 bias C-inits (registers, loaded once)
    #pragma unroll
    for (int mt = 0; mt < 2; ++mt) {
        const int ch = ((m16 >> 2) << 3) + (mt << 2) + (m16 & 3);   // sigma(16mt+m16)
        bf8 f0;
        #pragma unroll
        for (int j = 0; j < 8; ++j) {
            float v = 0.0f;
            if (q < 3) { if (j < 7) v = wT[ch*21 + q*7 + j]; }
            else       { if (j < 3) v = wL[ch*3 + j]; else if (j == 4) v = bT[ch]; }
            f0[j] = (short)bf_rne(v);
        }
        wA0[mt] = f0;
        {
            const f32x4 lo = *(const f32x4*)&w1[ch*32 + 8*q];
            const f32x4 hi = *(const f32x4*)&w1[ch*32 + 8*q + 4];
            bf8 g;
            #pragma unroll
            for (int j = 0; j < 4; ++j) { g[j] = (short)bf_rne(lo[j]); g[4+j] = (short)bf_rne(hi[j]); }
            wA1[mt] = g;
        }
        {
            const f32x4 lo = *(const f32x4*)&w2[ch*32 + 8*q];
            const f32x4 hi = *(const f32x4*)&w2[ch*32 + 8*q + 4];
            bf8 g;
            #pragma unroll
            for (int j = 0; j < 4; ++j) { g[j] = (short)bf_rne(lo[j]); g[4+j] = (short)bf_rne(hi[j]); }
            wA2[mt] = g;
        }
        // bias rows: computed row 16mt+4q+r -> logical sigma = 8q+4mt+r
        if (mt == 0) { cb1[0] = *(const f32x4*)&b1[8*q];     cb2[0] = *(const f32x4*)&b2[8*q]; }
        else         { cb1[1] = *(const f32x4*)&b1[8*q + 4]; cb2[1] = *(const f32x4*)&b2[8*q + 4]; }
    }
    // L3 A-frag: w3 in row 0 only (columns natural: sigma fixed-point)
    {
        bf8 g;
        #pragma unroll
        for (int j = 0; j < 8; ++j) {
            const float v = (m16 == 0) ? w3[8*q + j] : 0.0f;
            g[j] = (short)bf_rne(v);
        }
        aw3 = g;
    }
    // L3 bias C-init: row 0 (q==0, reg 0)
    f32x4 bias3v = {0.f, 0.f, 0.f, 0.f};
    if (q == 0) bias3v[0] = b3[0];

    f32x2 k001; k001[0] = 0.01f; k001[1] = 0.01f;

    const int img = blockIdx.y;
    const float* __restrict__ X = x + (size_t)img * RES;
    // XCD-aware row-pair swizzle: band of 32 consecutive pairs per XCD (256 % 8 == 0, bijective)
    const int bx = blockIdx.x;                       // 0..255 (row pair)
    const int i0 = (((bx & 7) << 5) | (bx >> 3)) << 1;   // first image row of the pair

    // ---- cooperative staging: 5 rows -> dual-parity bf16 (zero-padded; handles all edges) ----
    for (int w = tid; w < 5*2*RBW; w += 192) {
        const int r   = w / (2*RBW);      // 0..4: rows i0-3 .. i0+1
        const int rem = w - r*(2*RBW);
        const int cp  = rem / RBW;        // 0=A, 1=B
        const int wd  = rem - cp*RBW;
        const int srcrow = i0 - 3 + r;
        const int p0 = 2*wd - 4 + cp;     // A: 2wd-4 ; B: 2wd-3
        float f0 = 0.0f, f1 = 0.0f;
        if (srcrow >= 0) {
            if ((unsigned)p0 < (unsigned)WW)       f0 = X[srcrow*WW + p0];
            if ((unsigned)(p0+1) < (unsigned)WW)   f1 = X[srcrow*WW + p0 + 1];
        }
        rowbuf[r][cp][wd] = cvtpk(f0, f1);
    }
    __syncthreads();

    // per-lane LDS column: parity-selected copy, first word for tile 0
    const int cp = 1 - (m16 & 1);             // m16 odd -> copyA, even -> copyB
    const int w0 = (m16 + 1) >> 1;

    #pragma unroll 1
    for (int r2 = 0; r2 < 2; ++r2) {
        const unsigned* __restrict__ rb = &rowbuf[q + r2][cp][w0];
        const int pb0 = r2 << 9;          // predb offset for this output row

        #pragma unroll 1
        for (int u = 0; u < 8; ++u) {
            // ---- 4 independent tile chains (tiles 4u+0 .. 4u+3), R2-proven ILP form ----
            const bf8 pf0 = build_pf(rb, 4*u + 0, q);
            const bf8 pf1 = build_pf(rb, 4*u + 1, q);
            const bf8 pf2 = build_pf(rb, 4*u + 2, q);
            const bf8 pf3 = build_pf(rb, 4*u + 3, q);
            f32x4 acc0 = bias3v, acc1 = bias3v, acc2 = bias3v, acc3 = bias3v;
            run_pred_tile(wA0[0], wA0[1], wA1[0], wA1[1], wA2[0], wA2[1], aw3,
                          cb1[0], cb1[1], cb2[0], cb2[1], pf0, acc0, k001);
            run_pred_tile(wA0[0], wA0[1], wA1[0], wA1[1], wA2[0], wA2[1], aw3,
                          cb1[0], cb1[1], cb2[0], cb2[1], pf1, acc1, k001);
            run_pred_tile(wA0[0], wA0[1], wA1[0], wA1[1], wA2[0], wA2[1], aw3,
                          cb1[0], cb1[1], cb2[0], cb2[1], pf2, acc2, k001);
            run_pred_tile(wA0[0], wA0[1], wA1[0], wA1[1], wA2[0], wA2[1], aw3,
                          cb1[0], cb1[1], cb2[0], cb2[1], pf3, acc3, k001);

            // prediction for pixel m16 of each tile sits in row 0 = (q==0, reg 0);
            // clip here (matches reference clip-before-median), park in LDS
            if (q == 0) {
                predb[wv][pb0 + 64*u      + m16] = fminf(fmaxf(acc0[0], -1.0f), 1.0f);
                predb[wv][pb0 + 64*u + 16 + m16] = fminf(fmaxf(acc1[0], -1.0f), 1.0f);
                predb[wv][pb0 + 64*u + 32 + m16] = fminf(fmaxf(acc2[0], -1.0f), 1.0f);
                predb[wv][pb0 + 64*u + 48 + m16] = fminf(fmaxf(acc3[0], -1.0f), 1.0f);
            }
        }
    }

    __syncthreads();

    // ---- stats: all 192 threads cooperatively over the block's 1024 px (2 rows, contiguous) ----
    float sx = 0.0f, sd = 0.0f;
    const float* __restrict__ Xrow = X + i0*WW;
    for (int idx = tid; idx < PXB; idx += 192) {
        const float xv = Xrow[idx];                    // L1/L2-hot reload
        const float pa = predb[0][idx];
        const float pb = predb[1][idx];
        const float pc = predb[2][idx];
        const float med = fmaxf(fminf(pa, fmaxf(pb, pc)), fminf(pb, pc));
        const float v = xv - med + 1.0f;               // in (-1, 3)
        const float delta = ((v >= 2.0f) ? v - 2.0f : v) - 1.0f;   // == fmodf(v,2)-1 exactly
        int bx2 = (int)floorf((xv + 1.0f) * 128.0f);
        bx2 = bx2 < 0 ? 0 : (bx2 > 255 ? 255 : bx2);
        if (xv >= -1.0f && xv <= 1.0f) atomicAdd(&shx[bx2], 1u);
        int bd = (int)floorf((delta + 1.0f) * 128.0f);
        bd = bd < 0 ? 0 : (bd > 255 ? 255 : bd);
        if (delta >= -1.0f && delta <= 1.0f) atomicAdd(&shd[bd], 1u);
        sx += xv*xv; sd += delta*delta;
    }

    // ---- block reduction ----
    #pragma unroll
    for (int off = 32; off > 0; off >>= 1) {
        sx += __shfl_down(sx, off);
        sd += __shfl_down(sd, off);
    }
    if (lane == 0) { red[wv] = sx; red[4 + wv] = sd; }
    __syncthreads();
    if (tid == 0) {
        atomicAdd(&sums[0], red[0] + red[1] + red[2]);
        atomicAdd(&sums[1], red[4] + red[5] + red[6]);
    }
    for (int k = tid; k < NBINS; k += 192) {
        if (shx[k]) atomicAdd(&hist_x[img*NBINS + k], shx[k]);
        if (shd[k]) atomicAdd(&hist_d[img*NBINS + k], shd[k]);
    }
}

__global__ __launch_bounds__(256) void codec_final(
    const float* __restrict__ sums,
    const unsigned* __restrict__ hist_x,
    const unsigned* __restrict__ hist_d,
    float* __restrict__ out)
{
    __shared__ float red[16];
    const int tid = threadIdx.x;
    float ex = 0.0f, ed = 0.0f;
    const float inv_res = 1.0f / (float)RES;
    for (int k = tid; k < NIMG*NBINS; k += 256) {
        const unsigned hx = hist_x[k];
        const unsigned hd = hist_d[k];
        if (hx) { const float p = (float)hx * inv_res; ex -= p * log2f(p); }
        if (hd) { const float p = (float)hd * inv_res; ed -= p * log2f(p); }
    }
    #pragma unroll
    for (int off = 32; off > 0; off >>= 1) {
        ex += __shfl_down(ex, off);
        ed += __shfl_down(ed, off);
    }
    const int lane = tid & 63, wv = tid >> 6;
    if (lane == 0) { red[wv] = ex; red[8 + wv] = ed; }
    __syncthreads();
    if (tid == 0) {
        const float Ex = red[0] + red[1] + red[2] + red[3];
        const float Ed = red[8] + red[9] + red[10] + red[11];
        const float inv_n = 1.0f / (float)(NIMG * RES);
        out[0] = 255.0f * sqrtf(sums[1] * inv_n);   // loss1 (deltas)
        out[1] = 255.0f * sqrtf(sums[0] * inv_n);   // loss0 (x)
        out[2] = Ex / (8.0f * (float)NIMG);         // invCR0
        out[3] = Ed / (8.0f * (float)NIMG);         // invCR1
    }
}

extern "C" void kernel_launch(void* const* d_in, const int* in_sizes, int n_in,
                              void* d_out, int out_size, void* d_ws, size_t ws_size,
                              hipStream_t stream)
{
    const float* x = (const float*)d_in[0];
    const float* w[27];
    for (int k = 0; k < 27; ++k) w[k] = (const float*)d_in[1 + k];

    float*    sums   = (float*)d_ws;
    unsigned* hist_x = (unsigned*)((char*)d_ws + 16);
    unsigned* hist_d = hist_x + NIMG*NBINS;
    const size_t zbytes = 16 + (size_t)2*NIMG*NBINS*sizeof(unsigned);
    hipMemsetAsync(d_ws, 0, zbytes, stream);

    dim3 grid(HH/2, NIMG);
    codec_main<<<grid, dim3(192), 0, stream>>>(
        x,
        w[0],  w[1],  w[2],  w[3],  w[4],  w[5],  w[6],  w[7],  w[8],
        w[9],  w[10], w[11], w[12], w[13], w[14], w[15], w[16], w[17],
        w[18], w[19], w[20], w[21], w[22], w[23], w[24], w[25], w[26],
        sums, hist_x, hist_d);
    codec_final<<<1, dim3(256), 0, stream>>>(sums, hist_x, hist_d, (float*)d_out);
}